// Round 1
// 5805.522 us; speedup vs baseline: 2.2421x; 2.2421x over previous
//
#include <hip/hip_runtime.h>
#include <math.h>

// Transformer fwd: B=4, S=T=512, D=E=512, H=8, L=4, FF=2048, V=32000, fp32.
constexpr long S_   = 512;
constexpr long D_   = 512;
constexpr long SE_  = S_ * D_;        // 262144
constexpr long SS_  = S_ * S_;        // 262144
constexpr long BSE_ = 4 * SE_;        // 1048576
constexpr long DD_  = D_ * D_;        // 262144

typedef short bf16x8 __attribute__((ext_vector_type(8)));
typedef float f32x4  __attribute__((ext_vector_type(4)));

// fp32 -> bf16 RNE, and hi/lo split: v ~= bf2f(h) + bf2f(l), ~16-17 mantissa bits.
__device__ __forceinline__ ushort f2bf(float f) {
    unsigned u = __float_as_uint(f);
    u += 0x7fffu + ((u >> 16) & 1u);
    return (ushort)(u >> 16);
}
__device__ __forceinline__ float bf2f(ushort h) {
    return __uint_as_float((unsigned)h << 16);
}
__device__ __forceinline__ void split2(float v, ushort& h, ushort& l) {
    h = f2bf(v);
    l = f2bf(v - bf2f(h));
}

// ---------------------------------------------------------------------------
// MFMA batched strided GEMM, fp32 in/out via bf16x2 split (3 MFMAs per MAC tile).
// C = alpha * A @ B(^T) + bias, optional ReLU.
// A: M x K row-major. B: NN -> K x N (ldb=N); NT -> N x K (ldb=K).
// Block = 256 threads = 4 waves; tile BM x BN (128x128 or 64x64); BK = 32.
// LDS: K-contiguous bf16 planes [row][40] (pad 32->40: rows 80 B, 16 B-aligned,
// fragment ds_read_b128 lands 2-way bank alias = free).
// Fragment maps (gfx950, 16x16x32): A row=lane&15, k=8*(lane>>4)+e;
// B col=lane&15 (store B^T); D col=lane&15, row=4*(lane>>4)+reg.
// Grid: (M/BM, N/BN, z)  -- m-tile on x so co-resident blocks share B panels.
// ---------------------------------------------------------------------------
template <int BM, int BN, bool TRANSB>
__global__ __launch_bounds__(256)
void gemm_mfma(const float* __restrict__ A, const float* __restrict__ B,
               const float* __restrict__ bias, float* __restrict__ C,
               int M, int N, int K, int ldc,
               long Alo, long Ahi, long Blo, long Bhi, long biasHi,
               long Clo, long Chi, int zdiv, float alpha, int relu)
{
    (void)M;
    constexpr int LDK = 40;
    __shared__ __align__(16) ushort As_hi[BM * LDK];
    __shared__ __align__(16) ushort As_lo[BM * LDK];
    __shared__ __align__(16) ushort Bs_hi[BN * LDK];
    __shared__ __align__(16) ushort Bs_lo[BN * LDK];

    const int z  = blockIdx.z;
    const int zl = z % zdiv, zh = z / zdiv;
    A += (long)zl * Alo + (long)zh * Ahi;
    B += (long)zl * Blo + (long)zh * Bhi;
    C += (long)zl * Clo + (long)zh * Chi;
    if (bias) bias += (long)zh * biasHi;

    const int tid  = threadIdx.x;
    const int lane = tid & 63, wave = tid >> 6;
    const int wm = wave & 1, wn = wave >> 1;          // 2x2 waves over the tile
    constexpr int MT = BM / 32, NT = BN / 32;          // 16-wide frags per wave
    const int m0 = blockIdx.x * BM, n0 = blockIdx.y * BN;

    const int frow = lane & 15;                        // fragment row/col
    const int fko  = (lane >> 4) << 3;                 // k offset 0/8/16/24

    f32x4 acc[MT][NT] = {};

    const int r0 = tid >> 3, c4 = (tid & 7) << 2;      // row-major float4 loader

    for (int k0 = 0; k0 < K; k0 += 32) {
        // ---- stage A (BM x 32) ----
#pragma unroll
        for (int i = 0; i < BM / 32; i++) {
            const int r = r0 + 32 * i;
            const float4 v = *(const float4*)&A[(long)(m0 + r) * K + (k0 + c4)];
            ushort4 h4, l4;
            split2(v.x, h4.x, l4.x); split2(v.y, h4.y, l4.y);
            split2(v.z, h4.z, l4.z); split2(v.w, h4.w, l4.w);
            *(ushort4*)&As_hi[r * LDK + c4] = h4;
            *(ushort4*)&As_lo[r * LDK + c4] = l4;
        }
        // ---- stage B as B^T (BN x 32) ----
        if (TRANSB) {
#pragma unroll
            for (int i = 0; i < BN / 32; i++) {
                const int r = r0 + 32 * i;
                const float4 v = *(const float4*)&B[(long)(n0 + r) * K + (k0 + c4)];
                ushort4 h4, l4;
                split2(v.x, h4.x, l4.x); split2(v.y, h4.y, l4.y);
                split2(v.z, h4.z, l4.z); split2(v.w, h4.w, l4.w);
                *(ushort4*)&Bs_hi[r * LDK + c4] = h4;
                *(ushort4*)&Bs_lo[r * LDK + c4] = l4;
            }
        } else {
            // gather K-runs per column so LDS writes are b64-wide, K-contiguous
            constexpr int KC = BN / 8;                 // 128->16, 64->8
            const int c = tid & (BN - 1), kb = (tid / BN) * KC;
            float vv[KC];
#pragma unroll
            for (int j = 0; j < KC; j++)
                vv[j] = B[(long)(k0 + kb + j) * N + (n0 + c)];
#pragma unroll
            for (int j = 0; j < KC; j += 4) {
                ushort4 h4, l4;
                split2(vv[j + 0], h4.x, l4.x); split2(vv[j + 1], h4.y, l4.y);
                split2(vv[j + 2], h4.z, l4.z); split2(vv[j + 3], h4.w, l4.w);
                *(ushort4*)&Bs_hi[c * LDK + kb + j] = h4;
                *(ushort4*)&Bs_lo[c * LDK + kb + j] = l4;
            }
        }
        __syncthreads();

        bf16x8 ah[MT], al[MT];
#pragma unroll
        for (int i = 0; i < MT; i++) {
            const int r = wm * (BM / 2) + i * 16 + frow;
            ah[i] = *(const bf16x8*)&As_hi[r * LDK + fko];
            al[i] = *(const bf16x8*)&As_lo[r * LDK + fko];
        }
#pragma unroll
        for (int j = 0; j < NT; j++) {
            const int cq = wn * (BN / 2) + j * 16 + frow;
            const bf16x8 bh = *(const bf16x8*)&Bs_hi[cq * LDK + fko];
            const bf16x8 bl = *(const bf16x8*)&Bs_lo[cq * LDK + fko];
#pragma unroll
            for (int i = 0; i < MT; i++) {
                acc[i][j] = __builtin_amdgcn_mfma_f32_16x16x32_bf16(al[i], bh, acc[i][j], 0, 0, 0);
                acc[i][j] = __builtin_amdgcn_mfma_f32_16x16x32_bf16(ah[i], bl, acc[i][j], 0, 0, 0);
                acc[i][j] = __builtin_amdgcn_mfma_f32_16x16x32_bf16(ah[i], bh, acc[i][j], 0, 0, 0);
            }
        }
        __syncthreads();
    }

    // epilogue: D col=lane&15, row=4*(lane>>4)+q
    const int rb = (lane >> 4) << 2;
#pragma unroll
    for (int j = 0; j < NT; j++) {
        const int cc = n0 + wn * (BN / 2) + j * 16 + frow;
        const float bb = bias ? bias[cc] : 0.0f;
#pragma unroll
        for (int i = 0; i < MT; i++) {
            const long rr = m0 + wm * (BM / 2) + i * 16 + rb;
#pragma unroll
            for (int q = 0; q < 4; q++) {
                float v = acc[i][j][q] * alpha + bb;
                if (relu) v = fmaxf(v, 0.0f);
                C[(rr + q) * (long)ldc + cc] = v;
            }
        }
    }
}

// ---------------------------------------------------------------------------
// Softmax over attention rows (length 512), with additive pad / subsq masks.
// att layout: [z=h*4+b][t][s]. grid = (512 rows, 32 z), block 256.
// ---------------------------------------------------------------------------
__global__ __launch_bounds__(256)
void attn_softmax_kernel(float* __restrict__ att, const float* __restrict__ pad,
                         const float* __restrict__ subsq)
{
    __shared__ float sd[256];
    const int t = blockIdx.x, z = blockIdx.y, tid = threadIdx.x;
    const int b = z & 3;
    float* row = att + (long)z * SS_ + (long)t * 512;
    float v0 = row[tid]       + pad[b * 512 + tid];
    float v1 = row[tid + 256] + pad[b * 512 + tid + 256];
    if (subsq) { v0 += subsq[t * 512 + tid]; v1 += subsq[t * 512 + tid + 256]; }
    sd[tid] = fmaxf(v0, v1); __syncthreads();
    for (int s = 128; s > 0; s >>= 1) { if (tid < s) sd[tid] = fmaxf(sd[tid], sd[tid + s]); __syncthreads(); }
    const float mx = sd[0]; __syncthreads();
    const float e0 = expf(v0 - mx), e1 = expf(v1 - mx);
    sd[tid] = e0 + e1; __syncthreads();
    for (int s = 128; s > 0; s >>= 1) { if (tid < s) sd[tid] += sd[tid + s]; __syncthreads(); }
    const float inv = 1.0f / sd[0];
    row[tid] = e0 * inv; row[tid + 256] = e1 * inv;
}

// ---------------------------------------------------------------------------
// x = LN((a ? a : 0) + x) * g + b over rows of 512. grid = 2048, block 256.
// ---------------------------------------------------------------------------
__global__ __launch_bounds__(256)
void add_ln_kernel(const float* __restrict__ a, float* __restrict__ x,
                   const float* __restrict__ g, const float* __restrict__ b)
{
    __shared__ float sd[256];
    const long base = (long)blockIdx.x * 512;
    const int tid = threadIdx.x;
    float v0 = x[base + tid], v1 = x[base + tid + 256];
    if (a) { v0 += a[base + tid]; v1 += a[base + tid + 256]; }
    sd[tid] = v0 + v1; __syncthreads();
    for (int s = 128; s > 0; s >>= 1) { if (tid < s) sd[tid] += sd[tid + s]; __syncthreads(); }
    const float mean = sd[0] * (1.0f / 512.0f); __syncthreads();
    const float d0 = v0 - mean, d1 = v1 - mean;
    sd[tid] = d0 * d0 + d1 * d1; __syncthreads();
    for (int s = 128; s > 0; s >>= 1) { if (tid < s) sd[tid] += sd[tid + s]; __syncthreads(); }
    const float rstd = rsqrtf(sd[0] * (1.0f / 512.0f) + 1e-5f);
    x[base + tid]       = d0 * rstd * g[tid]       + b[tid];
    x[base + tid + 256] = d1 * rstd * g[tid + 256] + b[tid + 256];
}

// ---------------------------------------------------------------------------
// out[b,s,d] = emb[tok[b,s]][d] (+ sinusoidal PE if addpe). total = 2^20 elems.
// ---------------------------------------------------------------------------
__global__ __launch_bounds__(256)
void embed_kernel(const int* __restrict__ tok, const float* __restrict__ emb,
                  float* __restrict__ out, int addpe)
{
    const long idx = (long)blockIdx.x * 256 + threadIdx.x;
    const int d = (int)(idx & 511);
    const long bs = idx >> 9;
    const int s = (int)(bs & 511);
    float v = emb[(long)tok[bs] * 512 + d];
    if (addpe) {
        const int i = d >> 1;
        const float freq = powf(10000.0f, (2.0f * i) / 512.0f);
        const float ang = (float)s / freq;
        v += (d & 1) ? cosf(ang) : sinf(ang);
    }
    out[idx] = v;
}

// ---------------------------------------------------------------------------
// Stable softmax over vocab rows (32000), online max+sum: 2 global passes.
// grid = 2048, block 256.
// ---------------------------------------------------------------------------
__global__ __launch_bounds__(256)
void vocab_softmax_kernel(float* __restrict__ out)
{
    __shared__ float sm[256], ss[256];
    const long base = (long)blockIdx.x * 32000;
    const int tid = threadIdx.x;
    float mx = -3.0e38f, sum = 0.0f;
    for (int i = tid; i < 32000; i += 256) {
        const float v = out[base + i];
        const float nm = fmaxf(mx, v);
        sum = sum * expf(mx - nm) + expf(v - nm);
        mx = nm;
    }
    sm[tid] = mx; ss[tid] = sum; __syncthreads();
    for (int s = 128; s > 0; s >>= 1) {
        if (tid < s) {
            const float m2 = sm[tid + s], nm = fmaxf(sm[tid], m2);
            ss[tid] = ss[tid] * expf(sm[tid] - nm) + ss[tid + s] * expf(m2 - nm);
            sm[tid] = nm;
        }
        __syncthreads();
    }
    const float M = sm[0], inv = 1.0f / ss[0];
    for (int i = tid; i < 32000; i += 256)
        out[base + i] = expf(out[base + i] - M) * inv;
}

// ---------------------------------------------------------------------------
extern "C" void kernel_launch(void* const* d_in, const int* in_sizes, int n_in,
                              void* d_out, int out_size, void* d_ws, size_t ws_size,
                              hipStream_t stream)
{
    (void)in_sizes; (void)n_in; (void)out_size; (void)ws_size;
    const int*   src        = (const int*)  d_in[0];
    const int*   tgt        = (const int*)  d_in[1];
    const float* src_pad    = (const float*)d_in[2];
    const float* src_sub    = (const float*)d_in[3];
    const float* tgt_pad    = (const float*)d_in[4];
    const float* tgt_sub    = (const float*)d_in[5];
    const float* in_emb     = (const float*)d_in[6];
    const float* out_emb    = (const float*)d_in[7];
    const float* enc_attn_w = (const float*)d_in[8];
    const float* enc_attn_b = (const float*)d_in[9];
    const float* enc_proj_w = (const float*)d_in[10];
    const float* enc_proj_b = (const float*)d_in[11];
    const float* enc_ln1_g  = (const float*)d_in[12];
    const float* enc_ln1_b  = (const float*)d_in[13];
    const float* enc_ff1_w  = (const float*)d_in[14];
    const float* enc_ff1_b  = (const float*)d_in[15];
    const float* enc_ff2_w  = (const float*)d_in[16];
    const float* enc_ff2_b  = (const float*)d_in[17];
    const float* enc_ln2_g  = (const float*)d_in[18];
    const float* enc_ln2_b  = (const float*)d_in[19];
    const float* dec_self_w = (const float*)d_in[20];
    const float* dec_self_b = (const float*)d_in[21];
    const float* dec_self_pw= (const float*)d_in[22];
    const float* dec_self_pb= (const float*)d_in[23];
    const float* dec_ln1_g  = (const float*)d_in[24];
    const float* dec_ln1_b  = (const float*)d_in[25];
    const float* dec_memq_w = (const float*)d_in[26];
    const float* dec_memq_b = (const float*)d_in[27];
    const float* dec_mem_pw = (const float*)d_in[28];
    const float* dec_mem_pb = (const float*)d_in[29];
    const float* dec_ln2_g  = (const float*)d_in[30];
    const float* dec_ln2_b  = (const float*)d_in[31];
    const float* dec_ff1_w  = (const float*)d_in[32];
    const float* dec_ff1_b  = (const float*)d_in[33];
    const float* dec_ff2_w  = (const float*)d_in[34];
    const float* dec_ff2_b  = (const float*)d_in[35];
    const float* dec_ln3_g  = (const float*)d_in[36];
    const float* dec_ln3_b  = (const float*)d_in[37];
    const float* dec_norm_g = (const float*)d_in[38];
    const float* dec_norm_b = (const float*)d_in[39];
    const float* out_w      = (const float*)d_in[40];
    const float* out_b      = (const float*)d_in[41];
    float* out = (float*)d_out;

    // workspace layout (floats): total 41,943,040 = 168 MB
    float* ws   = (float*)d_ws;
    float* x    = ws;                  // 1,048,576   activations (B*S x D)
    float* tmp  = x    + 1048576;      // 1,048,576   pre-residual
    float* qkv  = tmp  + 1048576;      // 25,165,824  [m][h][b][t][e]; q-slot reused as cat
    float* att  = qkv  + 25165824;     // 8,388,608   [h*4+b][t][s]
    float* ffb  = att  + 8388608;      // 4,194,304   FF hidden (B*S x FF)
    float* memk = ffb  + 4194304;      // 1,048,576   encoder K, head 7, layer 3
    float* memv = memk + 1048576;      // 1,048,576

    const float SCALE = 0.044194173824159216f;  // 1/sqrt(512)

    auto gemm = [&](bool transB, const float* Ap, const float* Bp, const float* biasp, float* Cp,
                    int M, int N, int K, int ldc,
                    long Alo, long Ahi, long Blo, long Bhi, long biasHi,
                    long Clo, long Chi, int zcount, int zdiv, float alpha, int relu) {
        // 128x128 tiles when the launch still fills the chip; else 64x64.
        const bool big = (M % 128 == 0) && (N % 128 == 0) &&
                         ((long)(M / 128) * (N / 128) * zcount >= 192);
        if (big) {
            dim3 g(M / 128, N / 128, zcount), blk(256);
            if (transB)
                gemm_mfma<128,128,true><<<g, blk, 0, stream>>>(Ap, Bp, biasp, Cp, M, N, K, ldc,
                    Alo, Ahi, Blo, Bhi, biasHi, Clo, Chi, zdiv, alpha, relu);
            else
                gemm_mfma<128,128,false><<<g, blk, 0, stream>>>(Ap, Bp, biasp, Cp, M, N, K, ldc,
                    Alo, Ahi, Blo, Bhi, biasHi, Clo, Chi, zdiv, alpha, relu);
        } else {
            dim3 g(M / 64, N / 64, zcount), blk(256);
            if (transB)
                gemm_mfma<64,64,true><<<g, blk, 0, stream>>>(Ap, Bp, biasp, Cp, M, N, K, ldc,
                    Alo, Ahi, Blo, Bhi, biasHi, Clo, Chi, zdiv, alpha, relu);
            else
                gemm_mfma<64,64,false><<<g, blk, 0, stream>>>(Ap, Bp, biasp, Cp, M, N, K, ldc,
                    Alo, Ahi, Blo, Bhi, biasHi, Clo, Chi, zdiv, alpha, relu);
        }
    };

    // Full self-attention: QKV proj -> scores -> softmax -> P@V (direct into
    // cat layout, aliasing the q slot) -> output proj into tmp.
    auto self_attn = [&](const float* w, const float* bv, const float* pw, const float* pb,
                         const float* pad, const float* subsq) {
        // qkv[m][h][bt][e], z = m*8+h over 24 batches
        gemm(false, x, w, bv, qkv, 2048, 512, 512, 512,
             0, 0, 0, DD_, 512, 0, BSE_, 24, 1, 1.0f, 0);
        // scores: att[z=h*4+b] = q[z] @ k[z]^T * SCALE
        gemm(true, qkv + 16 * BSE_, qkv, nullptr, att, 512, 512, 512, 512,
             0, SE_, 0, SE_, 0, 0, SS_, 32, 1, SCALE, 0);
        attn_softmax_kernel<<<dim3(512, 32), 256, 0, stream>>>(att, pad, subsq);
        // o: cat[b*S+t][h*512+e] = p[z] @ v[z]; cat aliases q slot (q dead now)
        gemm(false, att, qkv + 8 * BSE_, nullptr, qkv + 16 * BSE_, 512, 512, 512, 4096,
             SS_, 4 * SS_, SE_, 4 * SE_, 0, 2097152L, 512, 32, 4, 1.0f, 0);
        gemm(false, qkv + 16 * BSE_, pw, pb, tmp, 2048, 512, 4096, 512,
             0, 0, 0, 0, 0, 0, 0, 1, 1, 1.0f, 0);
    };

    auto ffn = [&](const float* w1, const float* b1, const float* w2, const float* b2) {
        gemm(false, x, w1, b1, ffb, 2048, 2048, 512, 2048, 0, 0, 0, 0, 0, 0, 0, 1, 1, 1.0f, 1);
        gemm(false, ffb, w2, b2, tmp, 2048, 512, 2048, 512, 0, 0, 0, 0, 0, 0, 0, 1, 1, 1.0f, 0);
    };

    // ------------------------- encoder -------------------------
    embed_kernel<<<4096, 256, 0, stream>>>(src, in_emb, x, 1);
    for (int l = 0; l < 4; l++) {
        self_attn(enc_attn_w + (long)l * 24 * DD_, enc_attn_b + (long)l * 24 * 512,
                  enc_proj_w + (long)l * 4096 * 512, enc_proj_b + (long)l * 512,
                  src_pad, src_sub);
        add_ln_kernel<<<2048, 256, 0, stream>>>(tmp, x, enc_ln1_g + l * 512, enc_ln1_b + l * 512);
        ffn(enc_ff1_w + (long)l * 512 * 2048, enc_ff1_b + (long)l * 2048,
            enc_ff2_w + (long)l * 2048 * 512, enc_ff2_b + (long)l * 512);
        add_ln_kernel<<<2048, 256, 0, stream>>>(tmp, x, enc_ln2_g + l * 512, enc_ln2_b + l * 512);
    }
    // mem_k/v = K,V of LAST head (h=7) of last encoder layer: contiguous slabs
    hipMemcpyAsync(memk, qkv + 7 * BSE_,  BSE_ * sizeof(float), hipMemcpyDeviceToDevice, stream);
    hipMemcpyAsync(memv, qkv + 15 * BSE_, BSE_ * sizeof(float), hipMemcpyDeviceToDevice, stream);

    // ------------------------- decoder -------------------------
    embed_kernel<<<4096, 256, 0, stream>>>(tgt, out_emb, x, 0);  // no PE on decoder input
    for (int l = 0; l < 4; l++) {
        self_attn(dec_self_w + (long)l * 24 * DD_, dec_self_b + (long)l * 24 * 512,
                  dec_self_pw + (long)l * 4096 * 512, dec_self_pb + (long)l * 512,
                  tgt_pad, tgt_sub);
        add_ln_kernel<<<2048, 256, 0, stream>>>(tmp, x, dec_ln1_g + l * 512, dec_ln1_b + l * 512);
        // memory attention: q proj (8 batches) into qkv base
        gemm(false, x, dec_memq_w + (long)l * 8 * DD_, dec_memq_b + (long)l * 8 * 512, qkv,
             2048, 512, 512, 512, 0, 0, 0, DD_, 512, 0, BSE_, 8, 1, 1.0f, 0);
        // scores vs shared memk (per-b, no h stride)
        gemm(true, qkv, memk, nullptr, att, 512, 512, 512, 512,
             SE_, 4 * SE_, SE_, 0, 0, SS_, 4 * SS_, 32, 4, SCALE, 0);
        attn_softmax_kernel<<<dim3(512, 32), 256, 0, stream>>>(att, src_pad, nullptr);
        // o into cat (use free v-slot region at qkv + 8*BSE)
        gemm(false, att, memv, nullptr, qkv + 8 * BSE_, 512, 512, 512, 4096,
             SS_, 4 * SS_, SE_, 0, 0, 2097152L, 512, 32, 4, 1.0f, 0);
        gemm(false, qkv + 8 * BSE_, dec_mem_pw + (long)l * 4096 * 512, dec_mem_pb + (long)l * 512,
             tmp, 2048, 512, 4096, 512, 0, 0, 0, 0, 0, 0, 0, 1, 1, 1.0f, 0);
        add_ln_kernel<<<2048, 256, 0, stream>>>(tmp, x, dec_ln2_g + l * 512, dec_ln2_b + l * 512);
        ffn(dec_ff1_w + (long)l * 512 * 2048, dec_ff1_b + (long)l * 2048,
            dec_ff2_w + (long)l * 2048 * 512, dec_ff2_b + (long)l * 512);
        add_ln_kernel<<<2048, 256, 0, stream>>>(tmp, x, dec_ln3_g + l * 512, dec_ln3_b + l * 512);
    }
    // final LN (no residual) -> logits -> softmax
    add_ln_kernel<<<2048, 256, 0, stream>>>(nullptr, x, dec_norm_g, dec_norm_b);
    gemm(false, x, out_w, out_b, out, 2048, 32000, 512, 32000,
         0, 0, 0, 0, 0, 0, 0, 1, 1, 1.0f, 0);
    vocab_softmax_kernel<<<2048, 256, 0, stream>>>(out);
}